// Round 1
// baseline (1705.087 us; speedup 1.0000x reference)
//
#include <hip/hip_runtime.h>
#include <math.h>

// ---------------------------------------------------------------------------
// Problem constants
// ---------------------------------------------------------------------------
#define NB   128      // batch
#define HH   128
#define WW   128
#define HW   (HH*WW)          // 16384
#define POOLD 64              // pooled spatial
#define FC1_IN  8192          // 2*64*64
#define FC1_OUT 2048
#define FC2_OUT 1024

// workspace layout (in floats)
#define H1_OFF    0                       // 128*2*128*128 = 4194304
#define POOL_OFF  4194304                 // 128*8192      = 1048576
#define FC1_OFF   5242880                 // 128*2048      = 262144
#define FC2_OFF   5505024                 // 128*1024      = 131072
// total 5636096 floats = 21.5 MB

// ---------------------------------------------------------------------------
// Kernel 1: conv1  z=(x||mask) 9ch -> 2ch, 3x3, pad 1  ->  h1 (N,2,128,128)
// ---------------------------------------------------------------------------
__global__ __launch_bounds__(256) void conv1_kernel(
    const float* __restrict__ xin, const float* __restrict__ mask,
    const float* __restrict__ w1, const float* __restrict__ b1,
    float* __restrict__ h1)
{
    __shared__ float sw[164];           // 162 weights + 2 bias
    int tid = threadIdx.x;
    if (tid < 162) sw[tid] = w1[tid];
    if (tid < 2)   sw[162 + tid] = b1[tid];
    __syncthreads();

    int n    = blockIdx.y;
    int tile = blockIdx.x;                       // 0..63 (8x8 tiles of 16x16)
    int y = (tile >> 3) * 16 + (tid >> 4);
    int x = (tile & 7) * 16 + (tid & 15);

    float acc0 = sw[162], acc1 = sw[163];
    #pragma unroll
    for (int c = 0; c < 9; ++c) {
        const float* src = (c < 8) ? (xin + ((size_t)n * 8 + c) * HW)
                                   : (mask + (size_t)n * HW);
        #pragma unroll
        for (int ky = 0; ky < 3; ++ky) {
            int yy = y + ky - 1;
            if (yy < 0 || yy > 127) continue;
            #pragma unroll
            for (int kx = 0; kx < 3; ++kx) {
                int xx = x + kx - 1;
                if (xx < 0 || xx > 127) continue;
                float v = src[yy * WW + xx];
                acc0 += v * sw[c * 9 + ky * 3 + kx];
                acc1 += v * sw[81 + c * 9 + ky * 3 + kx];
            }
        }
    }
    size_t base = (size_t)n * (2 * HW) + y * WW + x;
    h1[base]      = acc0;
    h1[base + HW] = acc1;
}

// ---------------------------------------------------------------------------
// Kernel 2: fused  conv_off(recompute per px) -> modulated deform conv
//                  -> 1x1 conv + relu -> 2x2 maxpool  -> pooled (N, 2,64,64)
// ---------------------------------------------------------------------------
__device__ __forceinline__ float gat(const float* __restrict__ hc, int yi, int xi)
{
    return (yi >= 0 && yi < HH && xi >= 0 && xi < WW) ? hc[yi * WW + xi] : 0.f;
}

__global__ __launch_bounds__(256) void fused_dcn_kernel(
    const float* __restrict__ h1,
    const float* __restrict__ w_off,   // (27,2,3,3)
    const float* __restrict__ w_dcn,   // (2,2,3,3)
    const float* __restrict__ b_dcn,   // (2)
    const float* __restrict__ w2,      // (2,2,1,1)
    const float* __restrict__ b2,      // (2)
    float* __restrict__ pooled)        // (N, 8192) = (N,2,64,64)
{
    __shared__ float sw[530];
    int tid = threadIdx.x;
    for (int i = tid; i < 530; i += 256) {
        float v;
        if (i < 486)      v = w_off[i];
        else if (i < 522) v = w_dcn[i - 486];
        else if (i < 526) v = w2[i - 522];
        else if (i < 528) v = b_dcn[i - 526];
        else              v = b2[i - 528];
        sw[i] = v;
    }
    __syncthreads();
    const float* WOFF = sw;
    const float* WDCN = sw + 486;
    const float* W2   = sw + 522;
    const float* BDCN = sw + 526;
    const float* B2   = sw + 528;

    int n    = blockIdx.y;
    int tile = blockIdx.x;                        // 0..15 (4x4 tiles of 16x16 pooled px)
    int py0 = (tile >> 2) * 16 + (tid >> 4);      // pooled y
    int px0 = (tile & 3) * 16 + (tid & 15);       // pooled x
    const float* h0  = h1 + (size_t)n * (2 * HW);
    const float* hc1 = h0 + HW;

    float m0 = -1e30f, m1 = -1e30f;

    #pragma unroll
    for (int sy = 0; sy < 2; ++sy)
    #pragma unroll
    for (int sx = 0; sx < 2; ++sx) {
        int y = py0 * 2 + sy;
        int x = px0 * 2 + sx;

        // gather the 18 h1 taps for the dilated 3x3 offset conv (pad=3, dil=3)
        float hv[18];
        #pragma unroll
        for (int c = 0; c < 2; ++c)
        #pragma unroll
        for (int ky = 0; ky < 3; ++ky)
        #pragma unroll
        for (int kx = 0; kx < 3; ++kx) {
            int yy = y + (ky - 1) * 3;
            int xx = x + (kx - 1) * 3;
            float v = 0.f;
            if (yy >= 0 && yy < HH && xx >= 0 && xx < WW)
                v = (c == 0 ? h0 : hc1)[yy * WW + xx];
            hv[c * 9 + ky * 3 + kx] = v;
        }

        float acc0 = 0.f, acc1 = 0.f;
        #pragma unroll
        for (int k = 0; k < 9; ++k) {
            // om rows: dy = om[2k], dx = om[2k+1], mod = sigmoid(om[18+k])
            const float* wr_y = WOFF + (2 * k) * 18;
            const float* wr_x = WOFF + (2 * k + 1) * 18;
            const float* wr_m = WOFF + (18 + k) * 18;
            float dyv = 0.f, dxv = 0.f, mv = 0.f;
            #pragma unroll
            for (int t = 0; t < 18; ++t) {
                float h = hv[t];
                dyv += h * wr_y[t];
                dxv += h * wr_x[t];
                mv  += h * wr_m[t];
            }
            float mod = 1.f / (1.f + expf(-mv));

            float py = (float)y + (float)((k / 3 - 1) * 3) + dyv;
            float px = (float)x + (float)((k % 3 - 1) * 3) + dxv;
            float y0f = floorf(py), x0f = floorf(px);
            int   y0 = (int)y0f,   x0 = (int)x0f;
            float ly = py - y0f,   lx = px - x0f;
            float w00 = (1.f - ly) * (1.f - lx);
            float w01 = (1.f - ly) * lx;
            float w10 = ly * (1.f - lx);
            float w11 = ly * lx;

            #pragma unroll
            for (int c = 0; c < 2; ++c) {
                const float* hc = c ? hc1 : h0;
                float v = w00 * gat(hc, y0, x0)
                        + w01 * gat(hc, y0, x0 + 1)
                        + w10 * gat(hc, y0 + 1, x0)
                        + w11 * gat(hc, y0 + 1, x0 + 1);
                float s = v * mod;
                acc0 += WDCN[c * 9 + k] * s;        // o=0
                acc1 += WDCN[18 + c * 9 + k] * s;   // o=1
            }
        }
        float v0 = acc0 + BDCN[0];
        float v1 = acc1 + BDCN[1];
        float u0 = fmaxf(W2[0] * v0 + W2[1] * v1 + B2[0], 0.f);
        float u1 = fmaxf(W2[2] * v0 + W2[3] * v1 + B2[1], 0.f);
        m0 = fmaxf(m0, u0);
        m1 = fmaxf(m1, u1);
    }

    size_t pb = (size_t)n * FC1_IN + py0 * POOLD + px0;
    pooled[pb]        = m0;
    pooled[pb + 4096] = m1;
}

// ---------------------------------------------------------------------------
// Kernel 3: bias init for atomic GEMM outputs
// ---------------------------------------------------------------------------
__global__ void init_bias_kernel(float* __restrict__ out, const float* __restrict__ b,
                                 int cols, int total)
{
    int i = blockIdx.x * blockDim.x + threadIdx.x;
    if (i < total) out[i] = b[i & (cols - 1)];   // cols is a power of two
}

// ---------------------------------------------------------------------------
// Kernel 4: f32 GEMM  C(128 x Nc) += A(128 x K) @ B(Nc x K)^T   (split-K atomic)
//   BM=128 BN=64 BK=32, 256 threads, 8x4 microtile
// ---------------------------------------------------------------------------
__global__ __launch_bounds__(256) void gemm_splitk_kernel(
    const float* __restrict__ A, const float* __restrict__ B,
    float* __restrict__ C, int K, int Nc, int kchunk, int relu_a)
{
    __shared__ float As[32][128];
    __shared__ float Bs[32][64];

    int tid = threadIdx.x;
    int jt  = blockIdx.x;            // N tile
    int k0  = blockIdx.y * kchunk;

    int tx = tid & 15;               // 0..15 -> 4 cols each
    int ty = tid >> 4;               // 0..15 -> 8 rows each

    float acc[8][4];
    #pragma unroll
    for (int i = 0; i < 8; ++i)
        #pragma unroll
        for (int j = 0; j < 4; ++j) acc[i][j] = 0.f;

    int lr = tid >> 3;               // 0..31
    int lc = (tid & 7) << 2;         // 0,4,...,28

    for (int kk0 = 0; kk0 < kchunk; kk0 += 32) {
        int kbase = k0 + kk0;
        // stage A tile (128 x 32), transposed into As[k][m]
        #pragma unroll
        for (int p = 0; p < 4; ++p) {
            int row = lr + p * 32;
            float4 v = *(const float4*)(A + (size_t)row * K + kbase + lc);
            if (relu_a) {
                v.x = fmaxf(v.x, 0.f); v.y = fmaxf(v.y, 0.f);
                v.z = fmaxf(v.z, 0.f); v.w = fmaxf(v.w, 0.f);
            }
            As[lc + 0][row] = v.x; As[lc + 1][row] = v.y;
            As[lc + 2][row] = v.z; As[lc + 3][row] = v.w;
        }
        // stage B tile (64 x 32), transposed into Bs[k][n]
        #pragma unroll
        for (int p = 0; p < 2; ++p) {
            int row = lr + p * 32;
            float4 v = *(const float4*)(B + (size_t)(jt * 64 + row) * K + kbase + lc);
            Bs[lc + 0][row] = v.x; Bs[lc + 1][row] = v.y;
            Bs[lc + 2][row] = v.z; Bs[lc + 3][row] = v.w;
        }
        __syncthreads();

        #pragma unroll
        for (int kk = 0; kk < 32; ++kk) {
            float4 a0 = *(const float4*)&As[kk][ty * 8];
            float4 a1 = *(const float4*)&As[kk][ty * 8 + 4];
            float4 b  = *(const float4*)&Bs[kk][tx * 4];
            float av[8] = {a0.x, a0.y, a0.z, a0.w, a1.x, a1.y, a1.z, a1.w};
            float bv[4] = {b.x, b.y, b.z, b.w};
            #pragma unroll
            for (int i = 0; i < 8; ++i)
                #pragma unroll
                for (int j = 0; j < 4; ++j)
                    acc[i][j] += av[i] * bv[j];
        }
        __syncthreads();
    }

    #pragma unroll
    for (int i = 0; i < 8; ++i) {
        int row = ty * 8 + i;
        #pragma unroll
        for (int j = 0; j < 4; ++j) {
            int col = jt * 64 + tx * 4 + j;
            atomicAdd(C + (size_t)row * Nc + col, acc[i][j]);
        }
    }
}

// ---------------------------------------------------------------------------
// Kernel 5: io layer  out[n] = sigmoid( relu(fc2[n,:]) . io_w + io_b )
// ---------------------------------------------------------------------------
__global__ __launch_bounds__(256) void io_kernel(
    const float* __restrict__ fc2o, const float* __restrict__ io_w,
    const float* __restrict__ io_b, float* __restrict__ out)
{
    int n = blockIdx.x;
    int tid = threadIdx.x;
    float s = 0.f;
    #pragma unroll
    for (int k = tid; k < FC2_OUT; k += 256)
        s += fmaxf(fc2o[(size_t)n * FC2_OUT + k], 0.f) * io_w[k];
    #pragma unroll
    for (int off = 32; off > 0; off >>= 1)
        s += __shfl_down(s, off, 64);
    __shared__ float red[4];
    if ((tid & 63) == 0) red[tid >> 6] = s;
    __syncthreads();
    if (tid == 0) {
        float t = red[0] + red[1] + red[2] + red[3] + io_b[0];
        out[n] = 1.f / (1.f + expf(-t));
    }
}

// ---------------------------------------------------------------------------
// launch
// ---------------------------------------------------------------------------
extern "C" void kernel_launch(void* const* d_in, const int* in_sizes, int n_in,
                              void* d_out, int out_size, void* d_ws, size_t ws_size,
                              hipStream_t stream)
{
    const float* mask  = (const float*)d_in[0];
    const float* x     = (const float*)d_in[1];
    const float* w1    = (const float*)d_in[2];
    const float* b1    = (const float*)d_in[3];
    const float* w_off = (const float*)d_in[4];
    const float* w_dcn = (const float*)d_in[5];
    const float* b_dcn = (const float*)d_in[6];
    const float* w2    = (const float*)d_in[7];
    const float* b2    = (const float*)d_in[8];
    const float* fc1_w = (const float*)d_in[9];
    const float* fc1_b = (const float*)d_in[10];
    const float* fc2_w = (const float*)d_in[11];
    const float* fc2_b = (const float*)d_in[12];
    const float* io_w  = (const float*)d_in[13];
    const float* io_b  = (const float*)d_in[14];

    float* ws      = (float*)d_ws;
    float* h1      = ws + H1_OFF;
    float* pooled  = ws + POOL_OFF;
    float* fc1_out = ws + FC1_OFF;
    float* fc2_out = ws + FC2_OFF;
    float* out     = (float*)d_out;

    // conv1: (N,9,128,128) -> h1 (N,2,128,128)
    conv1_kernel<<<dim3(64, NB), 256, 0, stream>>>(x, mask, w1, b1, h1);

    // fused offset-conv + DCN + 1x1 relu + 2x2 maxpool -> pooled (N,8192)
    fused_dcn_kernel<<<dim3(16, NB), 256, 0, stream>>>(
        h1, w_off, w_dcn, b_dcn, w2, b2, pooled);

    // bias init for atomic accumulation
    init_bias_kernel<<<(NB * FC1_OUT + 255) / 256, 256, 0, stream>>>(
        fc1_out, fc1_b, FC1_OUT, NB * FC1_OUT);
    init_bias_kernel<<<(NB * FC2_OUT + 255) / 256, 256, 0, stream>>>(
        fc2_out, fc2_b, FC2_OUT, NB * FC2_OUT);

    // fc1: (128,8192)@(8192,2048) split-K 8 -> 32x8 = 256 blocks
    gemm_splitk_kernel<<<dim3(FC1_OUT / 64, 8), 256, 0, stream>>>(
        pooled, fc1_w, fc1_out, FC1_IN, FC1_OUT, FC1_IN / 8, 0);

    // fc2: relu(fc1) (128,2048)@(2048,1024) split-K 16 -> 16x16 = 256 blocks
    gemm_splitk_kernel<<<dim3(FC2_OUT / 64, 16), 256, 0, stream>>>(
        fc1_out, fc2_w, fc2_out, FC1_OUT, FC2_OUT, FC1_OUT / 16, 1);

    // io: relu(fc2) . io_w -> sigmoid -> out (128)
    io_kernel<<<NB, 256, 0, stream>>>(fc2_out, io_w, io_b, out);
}

// Round 2
// 586.662 us; speedup vs baseline: 2.9064x; 2.9064x over previous
//
#include <hip/hip_runtime.h>
#include <math.h>

// ---------------------------------------------------------------------------
// Problem constants
// ---------------------------------------------------------------------------
#define NB   128      // batch
#define HH   128
#define WW   128
#define HW   (HH*WW)          // 16384
#define POOLD 64              // pooled spatial
#define FC1_IN  8192          // 2*64*64
#define FC1_OUT 2048
#define FC2_OUT 1024

// workspace layout (in floats)
#define H1_OFF    0                       // 128*2*128*128 = 4194304
#define POOL_OFF  4194304                 // 128*8192      = 1048576
#define FC1_OFF   5242880                 // 128*2048      = 262144
#define FC2_OFF   5505024                 // 128*1024      = 131072

// ---------------------------------------------------------------------------
// Kernel 1: conv1  z=(x||mask) 9ch -> 2ch, 3x3, pad 1  ->  h1 (N,2,128,128)
// ---------------------------------------------------------------------------
__global__ __launch_bounds__(256) void conv1_kernel(
    const float* __restrict__ xin, const float* __restrict__ mask,
    const float* __restrict__ w1, const float* __restrict__ b1,
    float* __restrict__ h1)
{
    __shared__ float sw[164];           // 162 weights + 2 bias
    int tid = threadIdx.x;
    if (tid < 162) sw[tid] = w1[tid];
    if (tid < 2)   sw[162 + tid] = b1[tid];
    __syncthreads();

    int n    = blockIdx.y;
    int tile = blockIdx.x;                       // 0..63 (8x8 tiles of 16x16)
    int y = (tile >> 3) * 16 + (tid >> 4);
    int x = (tile & 7) * 16 + (tid & 15);

    float acc0 = sw[162], acc1 = sw[163];
    #pragma unroll
    for (int c = 0; c < 9; ++c) {
        const float* src = (c < 8) ? (xin + ((size_t)n * 8 + c) * HW)
                                   : (mask + (size_t)n * HW);
        #pragma unroll
        for (int ky = 0; ky < 3; ++ky) {
            int yy = y + ky - 1;
            if (yy < 0 || yy > 127) continue;
            #pragma unroll
            for (int kx = 0; kx < 3; ++kx) {
                int xx = x + kx - 1;
                if (xx < 0 || xx > 127) continue;
                float v = src[yy * WW + xx];
                acc0 += v * sw[c * 9 + ky * 3 + kx];
                acc1 += v * sw[81 + c * 9 + ky * 3 + kx];
            }
        }
    }
    size_t base = (size_t)n * (2 * HW) + y * WW + x;
    h1[base]      = acc0;
    h1[base + HW] = acc1;
}

// ---------------------------------------------------------------------------
// Kernel 2: fused  conv_off -> modulated deform conv -> 1x1+relu -> maxpool
//   LDS-staged: block = quarter image (32 full-res rows) + 8-row halo,
//   channels interleaved (y,x,c) so every tap is one ds_read_b64.
// ---------------------------------------------------------------------------
#define HALO 8
#define SROWS 48   // 32 + 2*8

__device__ __forceinline__ void fetch2(
    const float* __restrict__ sh, const float* __restrict__ h0,
    const float* __restrict__ hb, int row_lo, int row_hi,
    int yi, int xi, float& a, float& b)
{
    a = 0.f; b = 0.f;
    if (yi < 0 || yi >= HH || xi < 0 || xi >= WW) return;
    if (yi >= row_lo && yi < row_hi) {          // staged window (always, in practice)
        const float* p = sh + ((size_t)(yi - row_lo) * WW + xi) * 2;
        a = p[0]; b = p[1];
    } else {                                    // rare fallback: |offset| > HALO-5
        a = h0[yi * WW + xi];
        b = hb[yi * WW + xi];
    }
}

__global__ __launch_bounds__(256, 3) void fused_dcn_kernel(
    const float* __restrict__ h1,
    const float* __restrict__ w_off,   // (27,2,3,3)
    const float* __restrict__ w_dcn,   // (2,2,3,3)
    const float* __restrict__ b_dcn,   // (2)
    const float* __restrict__ w2,      // (2,2,1,1)
    const float* __restrict__ b2,      // (2)
    float* __restrict__ pooled)        // (N, 8192) = (N,2,64,64)
{
    __shared__ float sh[SROWS * WW * 2];   // 48 KB, interleaved (y,x,c)
    __shared__ float sw[530];

    int tid = threadIdx.x;
    int n   = blockIdx.y;
    int r0  = blockIdx.x * 32;             // full-res row base of this block

    for (int i = tid; i < 530; i += 256) {
        float v;
        if (i < 486)      v = w_off[i];
        else if (i < 522) v = w_dcn[i - 486];
        else if (i < 526) v = w2[i - 522];
        else if (i < 528) v = b_dcn[i - 526];
        else              v = b2[i - 528];
        sw[i] = v;
    }

    int row_lo = r0 - HALO;  if (row_lo < 0)   row_lo = 0;
    int row_hi = r0 + 32 + HALO; if (row_hi > HH) row_hi = HH;
    int rows = row_hi - row_lo;

    const float* h0 = h1 + (size_t)n * (2 * HW);
    const float* hb = h0 + HW;

    // stage h1 window: float4 per channel, interleave into LDS
    for (int idx = tid; idx < rows * 32; idx += 256) {
        int ry = idx >> 5;
        int x4 = (idx & 31) << 2;
        const float4 a = *(const float4*)(h0 + (size_t)(row_lo + ry) * WW + x4);
        const float4 b = *(const float4*)(hb + (size_t)(row_lo + ry) * WW + x4);
        float* d = sh + ((size_t)ry * WW + x4) * 2;
        d[0] = a.x; d[1] = b.x; d[2] = a.y; d[3] = b.y;
        d[4] = a.z; d[5] = b.z; d[6] = a.w; d[7] = b.w;
    }
    __syncthreads();

    const float* WOFF = sw;
    const float* WDCN = sw + 486;
    const float* W2   = sw + 522;
    const float* BDCN = sw + 526;
    const float* B2   = sw + 528;

    int pc  = tid & 63;                     // pooled col 0..63
    int prb = blockIdx.x * 16 + (tid >> 6); // pooled row base

    #pragma unroll 1
    for (int i = 0; i < 4; ++i) {
        int pr = prb + 4 * i;
        float m0 = -1e30f, m1 = -1e30f;

        #pragma unroll 1
        for (int s = 0; s < 4; ++s) {
            int y = pr * 2 + (s >> 1);
            int x = pc * 2 + (s & 1);

            // 9 dilated taps, both channels
            float hvx[9], hvy[9];
            #pragma unroll
            for (int t = 0; t < 9; ++t) {
                int yy = y + (t / 3 - 1) * 3;
                int xx = x + (t % 3 - 1) * 3;
                float a = 0.f, b = 0.f;
                if (yy >= 0 && yy < HH && xx >= 0 && xx < WW) {
                    const float* p = sh + ((size_t)(yy - row_lo) * WW + xx) * 2;
                    a = p[0]; b = p[1];
                }
                hvx[t] = a; hvy[t] = b;
            }

            float acc0 = 0.f, acc1 = 0.f;
            #pragma unroll 1
            for (int k = 0; k < 9; ++k) {
                const float* wy = WOFF + (2 * k) * 18;
                const float* wx = WOFF + (2 * k + 1) * 18;
                const float* wm = WOFF + (18 + k) * 18;
                float dyv = 0.f, dxv = 0.f, mv = 0.f;
                #pragma unroll
                for (int t = 0; t < 9; ++t) {
                    float ha = hvx[t], hcb = hvy[t];
                    dyv += ha * wy[t] + hcb * wy[9 + t];
                    dxv += ha * wx[t] + hcb * wx[9 + t];
                    mv  += ha * wm[t] + hcb * wm[9 + t];
                }
                float mod = 1.f / (1.f + __expf(-mv));

                float py  = (float)(y + (k / 3 - 1) * 3) + dyv;
                float pxx = (float)(x + (k % 3 - 1) * 3) + dxv;
                float y0f = floorf(py), x0f = floorf(pxx);
                int   y0 = (int)y0f,   x0 = (int)x0f;
                float ly = py - y0f,   lx = pxx - x0f;

                float a00, b00, a01, b01, a10, b10, a11, b11;
                fetch2(sh, h0, hb, row_lo, row_hi, y0,     x0,     a00, b00);
                fetch2(sh, h0, hb, row_lo, row_hi, y0,     x0 + 1, a01, b01);
                fetch2(sh, h0, hb, row_lo, row_hi, y0 + 1, x0,     a10, b10);
                fetch2(sh, h0, hb, row_lo, row_hi, y0 + 1, x0 + 1, a11, b11);

                float w00 = (1.f - ly) * (1.f - lx);
                float w01 = (1.f - ly) * lx;
                float w10 = ly * (1.f - lx);
                float w11 = ly * lx;
                float sA = (w00 * a00 + w01 * a01 + w10 * a10 + w11 * a11) * mod;
                float sB = (w00 * b00 + w01 * b01 + w10 * b10 + w11 * b11) * mod;

                acc0 += WDCN[k]      * sA + WDCN[9 + k]  * sB;
                acc1 += WDCN[18 + k] * sA + WDCN[27 + k] * sB;
            }

            float v0 = acc0 + BDCN[0];
            float v1 = acc1 + BDCN[1];
            float u0 = fmaxf(W2[0] * v0 + W2[1] * v1 + B2[0], 0.f);
            float u1 = fmaxf(W2[2] * v0 + W2[3] * v1 + B2[1], 0.f);
            m0 = fmaxf(m0, u0);
            m1 = fmaxf(m1, u1);
        }

        size_t pb = (size_t)n * FC1_IN + (size_t)pr * POOLD + pc;
        pooled[pb]        = m0;
        pooled[pb + 4096] = m1;
    }
}

// ---------------------------------------------------------------------------
// Kernel 3: bias init for atomic GEMM outputs
// ---------------------------------------------------------------------------
__global__ void init_bias_kernel(float* __restrict__ out, const float* __restrict__ b,
                                 int cols, int total)
{
    int i = blockIdx.x * blockDim.x + threadIdx.x;
    if (i < total) out[i] = b[i & (cols - 1)];   // cols is a power of two
}

// ---------------------------------------------------------------------------
// Kernel 4: f32 GEMM  C(128 x Nc) += A(128 x K) @ B(Nc x K)^T   (split-K atomic)
//   BM=128 BN=64 BK=32, 256 threads, 8x4 microtile
// ---------------------------------------------------------------------------
__global__ __launch_bounds__(256) void gemm_splitk_kernel(
    const float* __restrict__ A, const float* __restrict__ B,
    float* __restrict__ C, int K, int Nc, int kchunk, int relu_a)
{
    __shared__ float As[32][128];
    __shared__ float Bs[32][64];

    int tid = threadIdx.x;
    int jt  = blockIdx.x;            // N tile
    int k0  = blockIdx.y * kchunk;

    int tx = tid & 15;               // 0..15 -> 4 cols each
    int ty = tid >> 4;               // 0..15 -> 8 rows each

    float acc[8][4];
    #pragma unroll
    for (int i = 0; i < 8; ++i)
        #pragma unroll
        for (int j = 0; j < 4; ++j) acc[i][j] = 0.f;

    int lr = tid >> 3;               // 0..31
    int lc = (tid & 7) << 2;         // 0,4,...,28

    for (int kk0 = 0; kk0 < kchunk; kk0 += 32) {
        int kbase = k0 + kk0;
        #pragma unroll
        for (int p = 0; p < 4; ++p) {
            int row = lr + p * 32;
            float4 v = *(const float4*)(A + (size_t)row * K + kbase + lc);
            if (relu_a) {
                v.x = fmaxf(v.x, 0.f); v.y = fmaxf(v.y, 0.f);
                v.z = fmaxf(v.z, 0.f); v.w = fmaxf(v.w, 0.f);
            }
            As[lc + 0][row] = v.x; As[lc + 1][row] = v.y;
            As[lc + 2][row] = v.z; As[lc + 3][row] = v.w;
        }
        #pragma unroll
        for (int p = 0; p < 2; ++p) {
            int row = lr + p * 32;
            float4 v = *(const float4*)(B + (size_t)(jt * 64 + row) * K + kbase + lc);
            Bs[lc + 0][row] = v.x; Bs[lc + 1][row] = v.y;
            Bs[lc + 2][row] = v.z; Bs[lc + 3][row] = v.w;
        }
        __syncthreads();

        #pragma unroll
        for (int kk = 0; kk < 32; ++kk) {
            float4 a0 = *(const float4*)&As[kk][ty * 8];
            float4 a1 = *(const float4*)&As[kk][ty * 8 + 4];
            float4 b  = *(const float4*)&Bs[kk][tx * 4];
            float av[8] = {a0.x, a0.y, a0.z, a0.w, a1.x, a1.y, a1.z, a1.w};
            float bv[4] = {b.x, b.y, b.z, b.w};
            #pragma unroll
            for (int i = 0; i < 8; ++i)
                #pragma unroll
                for (int j = 0; j < 4; ++j)
                    acc[i][j] += av[i] * bv[j];
        }
        __syncthreads();
    }

    #pragma unroll
    for (int i = 0; i < 8; ++i) {
        int row = ty * 8 + i;
        #pragma unroll
        for (int j = 0; j < 4; ++j) {
            int col = jt * 64 + tx * 4 + j;
            atomicAdd(C + (size_t)row * Nc + col, acc[i][j]);
        }
    }
}

// ---------------------------------------------------------------------------
// Kernel 5: io layer  out[n] = sigmoid( relu(fc2[n,:]) . io_w + io_b )
// ---------------------------------------------------------------------------
__global__ __launch_bounds__(256) void io_kernel(
    const float* __restrict__ fc2o, const float* __restrict__ io_w,
    const float* __restrict__ io_b, float* __restrict__ out)
{
    int n = blockIdx.x;
    int tid = threadIdx.x;
    float s = 0.f;
    #pragma unroll
    for (int k = tid; k < FC2_OUT; k += 256)
        s += fmaxf(fc2o[(size_t)n * FC2_OUT + k], 0.f) * io_w[k];
    #pragma unroll
    for (int off = 32; off > 0; off >>= 1)
        s += __shfl_down(s, off, 64);
    __shared__ float red[4];
    if ((tid & 63) == 0) red[tid >> 6] = s;
    __syncthreads();
    if (tid == 0) {
        float t = red[0] + red[1] + red[2] + red[3] + io_b[0];
        out[n] = 1.f / (1.f + expf(-t));
    }
}

// ---------------------------------------------------------------------------
// launch
// ---------------------------------------------------------------------------
extern "C" void kernel_launch(void* const* d_in, const int* in_sizes, int n_in,
                              void* d_out, int out_size, void* d_ws, size_t ws_size,
                              hipStream_t stream)
{
    const float* mask  = (const float*)d_in[0];
    const float* x     = (const float*)d_in[1];
    const float* w1    = (const float*)d_in[2];
    const float* b1    = (const float*)d_in[3];
    const float* w_off = (const float*)d_in[4];
    const float* w_dcn = (const float*)d_in[5];
    const float* b_dcn = (const float*)d_in[6];
    const float* w2    = (const float*)d_in[7];
    const float* b2    = (const float*)d_in[8];
    const float* fc1_w = (const float*)d_in[9];
    const float* fc1_b = (const float*)d_in[10];
    const float* fc2_w = (const float*)d_in[11];
    const float* fc2_b = (const float*)d_in[12];
    const float* io_w  = (const float*)d_in[13];
    const float* io_b  = (const float*)d_in[14];

    float* ws      = (float*)d_ws;
    float* h1      = ws + H1_OFF;
    float* pooled  = ws + POOL_OFF;
    float* fc1_out = ws + FC1_OFF;
    float* fc2_out = ws + FC2_OFF;
    float* out     = (float*)d_out;

    // conv1: (N,9,128,128) -> h1 (N,2,128,128)
    conv1_kernel<<<dim3(64, NB), 256, 0, stream>>>(x, mask, w1, b1, h1);

    // fused offset-conv + DCN + 1x1 relu + 2x2 maxpool -> pooled (N,8192)
    fused_dcn_kernel<<<dim3(4, NB), 256, 0, stream>>>(
        h1, w_off, w_dcn, b_dcn, w2, b2, pooled);

    // bias init for atomic accumulation
    init_bias_kernel<<<(NB * FC1_OUT + 255) / 256, 256, 0, stream>>>(
        fc1_out, fc1_b, FC1_OUT, NB * FC1_OUT);
    init_bias_kernel<<<(NB * FC2_OUT + 255) / 256, 256, 0, stream>>>(
        fc2_out, fc2_b, FC2_OUT, NB * FC2_OUT);

    // fc1: (128,8192)@(8192,2048) split-K 8 -> 32x8 = 256 blocks
    gemm_splitk_kernel<<<dim3(FC1_OUT / 64, 8), 256, 0, stream>>>(
        pooled, fc1_w, fc1_out, FC1_IN, FC1_OUT, FC1_IN / 8, 0);

    // fc2: relu(fc1) (128,2048)@(2048,1024) split-K 16 -> 16x16 = 256 blocks
    gemm_splitk_kernel<<<dim3(FC2_OUT / 64, 16), 256, 0, stream>>>(
        fc1_out, fc2_w, fc2_out, FC1_OUT, FC2_OUT, FC1_OUT / 16, 1);

    // io: relu(fc2) . io_w -> sigmoid -> out (128)
    io_kernel<<<NB, 256, 0, stream>>>(fc2_out, io_w, io_b, out);
}

// Round 3
// 545.416 us; speedup vs baseline: 3.1262x; 1.0756x over previous
//
#include <hip/hip_runtime.h>
#include <math.h>

// ---------------------------------------------------------------------------
// Problem constants
// ---------------------------------------------------------------------------
#define NB   128      // batch
#define HH   128
#define WW   128
#define HW   (HH*WW)          // 16384
#define POOLD 64              // pooled spatial
#define FC1_IN  8192          // 2*64*64
#define FC1_OUT 2048
#define FC2_OUT 1024

// workspace layout (in floats)
#define H1_OFF    0                       // 128*2*128*128 = 4194304
#define POOL_OFF  4194304                 // 128*8192      = 1048576
#define FC1_OFF   5242880                 // 128*2048      = 262144
#define FC2_OFF   5505024                 // 128*1024      = 131072

// ---------------------------------------------------------------------------
// Kernel 1: conv1  z=(x||mask) 9ch -> 2ch, 3x3, pad 1  ->  h1 (N,2,128,128)
// ---------------------------------------------------------------------------
__global__ __launch_bounds__(256) void conv1_kernel(
    const float* __restrict__ xin, const float* __restrict__ mask,
    const float* __restrict__ w1, const float* __restrict__ b1,
    float* __restrict__ h1)
{
    __shared__ float sw[164];           // 162 weights + 2 bias
    int tid = threadIdx.x;
    if (tid < 162) sw[tid] = w1[tid];
    if (tid < 2)   sw[162 + tid] = b1[tid];
    __syncthreads();

    int n    = blockIdx.y;
    int tile = blockIdx.x;                       // 0..63 (8x8 tiles of 16x16)
    int y = (tile >> 3) * 16 + (tid >> 4);
    int x = (tile & 7) * 16 + (tid & 15);

    float acc0 = sw[162], acc1 = sw[163];
    #pragma unroll
    for (int c = 0; c < 9; ++c) {
        const float* src = (c < 8) ? (xin + ((size_t)n * 8 + c) * HW)
                                   : (mask + (size_t)n * HW);
        #pragma unroll
        for (int ky = 0; ky < 3; ++ky) {
            int yy = y + ky - 1;
            if (yy < 0 || yy > 127) continue;
            #pragma unroll
            for (int kx = 0; kx < 3; ++kx) {
                int xx = x + kx - 1;
                if (xx < 0 || xx > 127) continue;
                float v = src[yy * WW + xx];
                acc0 += v * sw[c * 9 + ky * 3 + kx];
                acc1 += v * sw[81 + c * 9 + ky * 3 + kx];
            }
        }
    }
    size_t base = (size_t)n * (2 * HW) + y * WW + x;
    h1[base]      = acc0;
    h1[base + HW] = acc1;
}

// ---------------------------------------------------------------------------
// Kernel 2: fused  conv_off -> modulated deform conv -> 1x1+relu -> maxpool
//   Block = 16 full-res rows (8 pooled rows) + 8-row halo -> 32 KB LDS,
//   grid 8 x NB = 1024 blocks -> 4 blocks/CU.
// ---------------------------------------------------------------------------
#define HALO 8

__device__ __forceinline__ void fetch2(
    const float* __restrict__ sh, const float* __restrict__ h0,
    const float* __restrict__ hb, int row_lo, int row_hi,
    int yi, int xi, float& a, float& b)
{
    a = 0.f; b = 0.f;
    if (yi < 0 || yi >= HH || xi < 0 || xi >= WW) return;
    if (yi >= row_lo && yi < row_hi) {          // staged window (always, in practice)
        const float* p = sh + ((size_t)(yi - row_lo) * WW + xi) * 2;
        a = p[0]; b = p[1];
    } else {                                    // rare fallback: |offset| > HALO-5
        a = h0[yi * WW + xi];
        b = hb[yi * WW + xi];
    }
}

__global__ __launch_bounds__(256, 4) void fused_dcn_kernel(
    const float* __restrict__ h1,
    const float* __restrict__ w_off,   // (27,2,3,3)
    const float* __restrict__ w_dcn,   // (2,2,3,3)
    const float* __restrict__ b_dcn,   // (2)
    const float* __restrict__ w2,      // (2,2,1,1)
    const float* __restrict__ b2,      // (2)
    float* __restrict__ pooled)        // (N, 8192) = (N,2,64,64)
{
    __shared__ float sh[32 * WW * 2];      // 32 KB, interleaved (y,x,c)
    __shared__ float sw[530];

    int tid = threadIdx.x;
    int n   = blockIdx.y;
    int r0  = blockIdx.x * 16;             // full-res row base of this block

    for (int i = tid; i < 530; i += 256) {
        float v;
        if (i < 486)      v = w_off[i];
        else if (i < 522) v = w_dcn[i - 486];
        else if (i < 526) v = w2[i - 522];
        else if (i < 528) v = b_dcn[i - 526];
        else              v = b2[i - 528];
        sw[i] = v;
    }

    int row_lo = r0 - HALO;       if (row_lo < 0)   row_lo = 0;
    int row_hi = r0 + 16 + HALO;  if (row_hi > HH)  row_hi = HH;
    int rows = row_hi - row_lo;

    const float* h0 = h1 + (size_t)n * (2 * HW);
    const float* hb = h0 + HW;

    // stage h1 window: float4 per channel, interleave into LDS
    for (int idx = tid; idx < rows * 32; idx += 256) {
        int ry = idx >> 5;
        int x4 = (idx & 31) << 2;
        const float4 a = *(const float4*)(h0 + (size_t)(row_lo + ry) * WW + x4);
        const float4 b = *(const float4*)(hb + (size_t)(row_lo + ry) * WW + x4);
        float* d = sh + ((size_t)ry * WW + x4) * 2;
        d[0] = a.x; d[1] = b.x; d[2] = a.y; d[3] = b.y;
        d[4] = a.z; d[5] = b.z; d[6] = a.w; d[7] = b.w;
    }
    __syncthreads();

    const float* WOFF = sw;
    const float* WDCN = sw + 486;
    const float* W2   = sw + 522;
    const float* BDCN = sw + 526;
    const float* B2   = sw + 528;

    int pc  = tid & 63;                     // pooled col 0..63
    int prb = blockIdx.x * 8 + (tid >> 6);  // pooled row base (warp-row 0..3)

    #pragma unroll 1
    for (int i = 0; i < 2; ++i) {
        int pr = prb + 4 * i;
        float m0 = -1e30f, m1 = -1e30f;

        #pragma unroll 1
        for (int s = 0; s < 4; ++s) {
            int y = pr * 2 + (s >> 1);
            int x = pc * 2 + (s & 1);

            // 9 dilated taps, both channels
            float hvx[9], hvy[9];
            #pragma unroll
            for (int t = 0; t < 9; ++t) {
                int yy = y + (t / 3 - 1) * 3;
                int xx = x + (t % 3 - 1) * 3;
                float a = 0.f, b = 0.f;
                if (yy >= 0 && yy < HH && xx >= 0 && xx < WW) {
                    const float* p = sh + ((size_t)(yy - row_lo) * WW + xx) * 2;
                    a = p[0]; b = p[1];
                }
                hvx[t] = a; hvy[t] = b;
            }

            float acc0 = 0.f, acc1 = 0.f;
            #pragma unroll 1
            for (int k = 0; k < 9; ++k) {
                const float* wy = WOFF + (2 * k) * 18;
                const float* wx = WOFF + (2 * k + 1) * 18;
                const float* wm = WOFF + (18 + k) * 18;
                float dyv = 0.f, dxv = 0.f, mv = 0.f;
                #pragma unroll
                for (int t = 0; t < 9; ++t) {
                    float ha = hvx[t], hcb = hvy[t];
                    dyv += ha * wy[t] + hcb * wy[9 + t];
                    dxv += ha * wx[t] + hcb * wx[9 + t];
                    mv  += ha * wm[t] + hcb * wm[9 + t];
                }
                float mod = 1.f / (1.f + __expf(-mv));

                float py  = (float)(y + (k / 3 - 1) * 3) + dyv;
                float pxx = (float)(x + (k % 3 - 1) * 3) + dxv;
                float y0f = floorf(py), x0f = floorf(pxx);
                int   y0 = (int)y0f,   x0 = (int)x0f;
                float ly = py - y0f,   lx = pxx - x0f;

                float a00, b00, a01, b01, a10, b10, a11, b11;
                fetch2(sh, h0, hb, row_lo, row_hi, y0,     x0,     a00, b00);
                fetch2(sh, h0, hb, row_lo, row_hi, y0,     x0 + 1, a01, b01);
                fetch2(sh, h0, hb, row_lo, row_hi, y0 + 1, x0,     a10, b10);
                fetch2(sh, h0, hb, row_lo, row_hi, y0 + 1, x0 + 1, a11, b11);

                float w00 = (1.f - ly) * (1.f - lx);
                float w01 = (1.f - ly) * lx;
                float w10 = ly * (1.f - lx);
                float w11 = ly * lx;
                float sA = (w00 * a00 + w01 * a01 + w10 * a10 + w11 * a11) * mod;
                float sB = (w00 * b00 + w01 * b01 + w10 * b10 + w11 * b11) * mod;

                acc0 += WDCN[k]      * sA + WDCN[9 + k]  * sB;
                acc1 += WDCN[18 + k] * sA + WDCN[27 + k] * sB;
            }

            float v0 = acc0 + BDCN[0];
            float v1 = acc1 + BDCN[1];
            float u0 = fmaxf(W2[0] * v0 + W2[1] * v1 + B2[0], 0.f);
            float u1 = fmaxf(W2[2] * v0 + W2[3] * v1 + B2[1], 0.f);
            m0 = fmaxf(m0, u0);
            m1 = fmaxf(m1, u1);
        }

        size_t pb = (size_t)n * FC1_IN + (size_t)pr * POOLD + pc;
        pooled[pb]        = m0;
        pooled[pb + 4096] = m1;
    }
}

// ---------------------------------------------------------------------------
// Kernel 3: bias init for both atomic GEMM outputs (fused)
// ---------------------------------------------------------------------------
__global__ void init_bias2_kernel(
    float* __restrict__ o1, const float* __restrict__ bb1,
    float* __restrict__ o2, const float* __restrict__ bb2)
{
    int i = blockIdx.x * blockDim.x + threadIdx.x;
    if (i < NB * FC1_OUT) o1[i] = bb1[i & (FC1_OUT - 1)];
    if (i < NB * FC2_OUT) o2[i] = bb2[i & (FC2_OUT - 1)];
}

// ---------------------------------------------------------------------------
// Kernel 4: f32 GEMM  C(128 x Nc) += A(128 x K) @ B(Nc x K)^T   (split-K atomic)
//   BM=128 BN=64 BK=32, 256 threads, 8x4 microtile
// ---------------------------------------------------------------------------
__global__ __launch_bounds__(256) void gemm_splitk_kernel(
    const float* __restrict__ A, const float* __restrict__ B,
    float* __restrict__ C, int K, int Nc, int kchunk, int relu_a)
{
    __shared__ float As[32][128];
    __shared__ float Bs[32][64];

    int tid = threadIdx.x;
    int jt  = blockIdx.x;            // N tile
    int k0  = blockIdx.y * kchunk;

    int tx = tid & 15;               // 0..15 -> 4 cols each
    int ty = tid >> 4;               // 0..15 -> 8 rows each

    float acc[8][4];
    #pragma unroll
    for (int i = 0; i < 8; ++i)
        #pragma unroll
        for (int j = 0; j < 4; ++j) acc[i][j] = 0.f;

    int lr = tid >> 3;               // 0..31
    int lc = (tid & 7) << 2;         // 0,4,...,28

    for (int kk0 = 0; kk0 < kchunk; kk0 += 32) {
        int kbase = k0 + kk0;
        #pragma unroll
        for (int p = 0; p < 4; ++p) {
            int row = lr + p * 32;
            float4 v = *(const float4*)(A + (size_t)row * K + kbase + lc);
            if (relu_a) {
                v.x = fmaxf(v.x, 0.f); v.y = fmaxf(v.y, 0.f);
                v.z = fmaxf(v.z, 0.f); v.w = fmaxf(v.w, 0.f);
            }
            As[lc + 0][row] = v.x; As[lc + 1][row] = v.y;
            As[lc + 2][row] = v.z; As[lc + 3][row] = v.w;
        }
        #pragma unroll
        for (int p = 0; p < 2; ++p) {
            int row = lr + p * 32;
            float4 v = *(const float4*)(B + (size_t)(jt * 64 + row) * K + kbase + lc);
            Bs[lc + 0][row] = v.x; Bs[lc + 1][row] = v.y;
            Bs[lc + 2][row] = v.z; Bs[lc + 3][row] = v.w;
        }
        __syncthreads();

        #pragma unroll
        for (int kk = 0; kk < 32; ++kk) {
            float4 a0 = *(const float4*)&As[kk][ty * 8];
            float4 a1 = *(const float4*)&As[kk][ty * 8 + 4];
            float4 b  = *(const float4*)&Bs[kk][tx * 4];
            float av[8] = {a0.x, a0.y, a0.z, a0.w, a1.x, a1.y, a1.z, a1.w};
            float bv[4] = {b.x, b.y, b.z, b.w};
            #pragma unroll
            for (int i = 0; i < 8; ++i)
                #pragma unroll
                for (int j = 0; j < 4; ++j)
                    acc[i][j] += av[i] * bv[j];
        }
        __syncthreads();
    }

    #pragma unroll
    for (int i = 0; i < 8; ++i) {
        int row = ty * 8 + i;
        #pragma unroll
        for (int j = 0; j < 4; ++j) {
            int col = jt * 64 + tx * 4 + j;
            atomicAdd(C + (size_t)row * Nc + col, acc[i][j]);
        }
    }
}

// ---------------------------------------------------------------------------
// Kernel 5: io layer  out[n] = sigmoid( relu(fc2[n,:]) . io_w + io_b )
// ---------------------------------------------------------------------------
__global__ __launch_bounds__(256) void io_kernel(
    const float* __restrict__ fc2o, const float* __restrict__ io_w,
    const float* __restrict__ io_b, float* __restrict__ out)
{
    int n = blockIdx.x;
    int tid = threadIdx.x;
    float s = 0.f;
    #pragma unroll
    for (int k = tid; k < FC2_OUT; k += 256)
        s += fmaxf(fc2o[(size_t)n * FC2_OUT + k], 0.f) * io_w[k];
    #pragma unroll
    for (int off = 32; off > 0; off >>= 1)
        s += __shfl_down(s, off, 64);
    __shared__ float red[4];
    if ((tid & 63) == 0) red[tid >> 6] = s;
    __syncthreads();
    if (tid == 0) {
        float t = red[0] + red[1] + red[2] + red[3] + io_b[0];
        out[n] = 1.f / (1.f + expf(-t));
    }
}

// ---------------------------------------------------------------------------
// launch
// ---------------------------------------------------------------------------
extern "C" void kernel_launch(void* const* d_in, const int* in_sizes, int n_in,
                              void* d_out, int out_size, void* d_ws, size_t ws_size,
                              hipStream_t stream)
{
    const float* mask  = (const float*)d_in[0];
    const float* x     = (const float*)d_in[1];
    const float* w1    = (const float*)d_in[2];
    const float* b1    = (const float*)d_in[3];
    const float* w_off = (const float*)d_in[4];
    const float* w_dcn = (const float*)d_in[5];
    const float* b_dcn = (const float*)d_in[6];
    const float* w2    = (const float*)d_in[7];
    const float* b2    = (const float*)d_in[8];
    const float* fc1_w = (const float*)d_in[9];
    const float* fc1_b = (const float*)d_in[10];
    const float* fc2_w = (const float*)d_in[11];
    const float* fc2_b = (const float*)d_in[12];
    const float* io_w  = (const float*)d_in[13];
    const float* io_b  = (const float*)d_in[14];

    float* ws      = (float*)d_ws;
    float* h1      = ws + H1_OFF;
    float* pooled  = ws + POOL_OFF;
    float* fc1_out = ws + FC1_OFF;
    float* fc2_out = ws + FC2_OFF;
    float* out     = (float*)d_out;

    // conv1: (N,9,128,128) -> h1 (N,2,128,128)
    conv1_kernel<<<dim3(64, NB), 256, 0, stream>>>(x, mask, w1, b1, h1);

    // fused offset-conv + DCN + 1x1 relu + 2x2 maxpool -> pooled (N,8192)
    fused_dcn_kernel<<<dim3(8, NB), 256, 0, stream>>>(
        h1, w_off, w_dcn, b_dcn, w2, b2, pooled);

    // bias init for atomic accumulation (fused)
    init_bias2_kernel<<<(NB * FC1_OUT + 255) / 256, 256, 0, stream>>>(
        fc1_out, fc1_b, fc2_out, fc2_b);

    // fc1: (128,8192)@(8192,2048) split-K 16 -> 32x16 = 512 blocks
    gemm_splitk_kernel<<<dim3(FC1_OUT / 64, 16), 256, 0, stream>>>(
        pooled, fc1_w, fc1_out, FC1_IN, FC1_OUT, FC1_IN / 16, 0);

    // fc2: relu(fc1) (128,2048)@(2048,1024) split-K 16 -> 16x16 = 256 blocks
    gemm_splitk_kernel<<<dim3(FC2_OUT / 64, 16), 256, 0, stream>>>(
        fc1_out, fc2_w, fc2_out, FC1_OUT, FC2_OUT, FC1_OUT / 16, 1);

    // io: relu(fc2) . io_w -> sigmoid -> out (128)
    io_kernel<<<NB, 256, 0, stream>>>(fc2_out, io_w, io_b, out);
}

// Round 4
// 462.180 us; speedup vs baseline: 3.6892x; 1.1801x over previous
//
#include <hip/hip_runtime.h>
#include <math.h>

// ---------------------------------------------------------------------------
// Problem constants
// ---------------------------------------------------------------------------
#define NB   128      // batch
#define HH   128
#define WW   128
#define HW   (HH*WW)          // 16384
#define POOLD 64              // pooled spatial
#define FC1_IN  8192          // 2*64*64
#define FC1_OUT 2048
#define FC2_OUT 1024

// workspace layout (in floats)
#define H1_OFF    0                       // 128*2*128*128 = 4194304
#define POOL_OFF  4194304                 // 128*8192      = 1048576
#define FC1_OFF   5242880                 // 128*2048      = 262144
#define FC2_OFF   5505024                 // 128*1024      = 131072

// ---------------------------------------------------------------------------
// Kernel 1: conv1  z=(x||mask) 9ch -> 2ch, 3x3, pad 1  ->  h1 (N,2,128,128)
//   LDS-staged: block = 8 output rows x 128 cols, stages 9ch x 10 rows.
//   Each thread computes 4 vertically adjacent pixels (tap reuse).
// ---------------------------------------------------------------------------
__global__ __launch_bounds__(256) void conv1_kernel(
    const float* __restrict__ xin, const float* __restrict__ mask,
    const float* __restrict__ w1, const float* __restrict__ b1,
    float* __restrict__ h1)
{
    __shared__ float sw[164];              // 162 weights + 2 bias
    __shared__ float sh[9][10][132];       // ch x in-row x (col+1 pad each side)

    int tid = threadIdx.x;
    int n   = blockIdx.y;
    int r0  = blockIdx.x * 8;              // first output row of this block

    if (tid < 162) sw[tid] = w1[tid];
    if (tid < 2)   sw[162 + tid] = b1[tid];

    // zero the edge columns (global col -1 and 128)
    for (int i = tid; i < 90; i += 256) {
        int c  = i / 10;
        int ry = i - c * 10;
        sh[c][ry][0]   = 0.f;
        sh[c][ry][129] = 0.f;
    }

    // stage 9 x 10 x 128 floats as float4 rows (12 indep loads/thread)
    for (int idx = tid; idx < 2880; idx += 256) {
        int c   = idx / 320;
        int rem = idx - c * 320;
        int ry  = rem >> 5;
        int x4  = (rem & 31) << 2;
        int g   = r0 - 1 + ry;             // global input row
        float4 v = make_float4(0.f, 0.f, 0.f, 0.f);
        if (g >= 0 && g < HH) {
            const float* src = (c < 8) ? (xin + ((size_t)n * 8 + c) * HW)
                                       : (mask + (size_t)n * HW);
            v = *(const float4*)(src + (size_t)g * WW + x4);
        }
        float* d = &sh[c][ry][x4 + 1];
        d[0] = v.x; d[1] = v.y; d[2] = v.z; d[3] = v.w;
    }
    __syncthreads();

    int x  = tid & 127;                    // output col
    int yb = (tid >> 7) * 4;               // 0 or 4: first of 4 output rows

    float acc[4][2];
    #pragma unroll
    for (int r = 0; r < 4; ++r) { acc[r][0] = sw[162]; acc[r][1] = sw[163]; }

    for (int c = 0; c < 9; ++c) {
        float v[6][3];
        #pragma unroll
        for (int iy = 0; iy < 6; ++iy)
            #pragma unroll
            for (int kx = 0; kx < 3; ++kx)
                v[iy][kx] = sh[c][yb + iy][x + kx];
        #pragma unroll
        for (int r = 0; r < 4; ++r)
            #pragma unroll
            for (int ky = 0; ky < 3; ++ky)
                #pragma unroll
                for (int kx = 0; kx < 3; ++kx) {
                    float t = v[r + ky][kx];
                    acc[r][0] += t * sw[c * 9 + ky * 3 + kx];
                    acc[r][1] += t * sw[81 + c * 9 + ky * 3 + kx];
                }
    }

    #pragma unroll
    for (int r = 0; r < 4; ++r) {
        size_t base = (size_t)n * (2 * HW) + (size_t)(r0 + yb + r) * WW + x;
        h1[base]      = acc[r][0];
        h1[base + HW] = acc[r][1];
    }
}

// ---------------------------------------------------------------------------
// Kernel 2: fused  conv_off -> modulated deform conv -> 1x1+relu -> maxpool
//   Block = 16 full-res rows (8 pooled rows) + 8-row halo -> 32 KB LDS,
//   grid 8 x NB = 1024 blocks -> 4 blocks/CU.
// ---------------------------------------------------------------------------
#define HALO 8

__device__ __forceinline__ void fetch2(
    const float* __restrict__ sh, const float* __restrict__ h0,
    const float* __restrict__ hb, int row_lo, int row_hi,
    int yi, int xi, float& a, float& b)
{
    a = 0.f; b = 0.f;
    if (yi < 0 || yi >= HH || xi < 0 || xi >= WW) return;
    if (yi >= row_lo && yi < row_hi) {          // staged window (always, in practice)
        const float* p = sh + ((size_t)(yi - row_lo) * WW + xi) * 2;
        a = p[0]; b = p[1];
    } else {                                    // rare fallback: |offset| > HALO-5
        a = h0[yi * WW + xi];
        b = hb[yi * WW + xi];
    }
}

__global__ __launch_bounds__(256, 4) void fused_dcn_kernel(
    const float* __restrict__ h1,
    const float* __restrict__ w_off,   // (27,2,3,3)
    const float* __restrict__ w_dcn,   // (2,2,3,3)
    const float* __restrict__ b_dcn,   // (2)
    const float* __restrict__ w2,      // (2,2,1,1)
    const float* __restrict__ b2,      // (2)
    float* __restrict__ pooled)        // (N, 8192) = (N,2,64,64)
{
    __shared__ float sh[32 * WW * 2];      // 32 KB, interleaved (y,x,c)
    __shared__ float sw[530];

    int tid = threadIdx.x;
    int n   = blockIdx.y;
    int r0  = blockIdx.x * 16;             // full-res row base of this block

    for (int i = tid; i < 530; i += 256) {
        float v;
        if (i < 486)      v = w_off[i];
        else if (i < 522) v = w_dcn[i - 486];
        else if (i < 526) v = w2[i - 522];
        else if (i < 528) v = b_dcn[i - 526];
        else              v = b2[i - 528];
        sw[i] = v;
    }

    int row_lo = r0 - HALO;       if (row_lo < 0)   row_lo = 0;
    int row_hi = r0 + 16 + HALO;  if (row_hi > HH)  row_hi = HH;
    int rows = row_hi - row_lo;

    const float* h0 = h1 + (size_t)n * (2 * HW);
    const float* hb = h0 + HW;

    // stage h1 window: float4 per channel, interleave into LDS
    for (int idx = tid; idx < rows * 32; idx += 256) {
        int ry = idx >> 5;
        int x4 = (idx & 31) << 2;
        const float4 a = *(const float4*)(h0 + (size_t)(row_lo + ry) * WW + x4);
        const float4 b = *(const float4*)(hb + (size_t)(row_lo + ry) * WW + x4);
        float* d = sh + ((size_t)ry * WW + x4) * 2;
        d[0] = a.x; d[1] = b.x; d[2] = a.y; d[3] = b.y;
        d[4] = a.z; d[5] = b.z; d[6] = a.w; d[7] = b.w;
    }
    __syncthreads();

    const float* WOFF = sw;
    const float* WDCN = sw + 486;
    const float* W2   = sw + 522;
    const float* BDCN = sw + 526;
    const float* B2   = sw + 528;

    int pc  = tid & 63;                     // pooled col 0..63
    int prb = blockIdx.x * 8 + (tid >> 6);  // pooled row base (warp-row 0..3)

    #pragma unroll 1
    for (int i = 0; i < 2; ++i) {
        int pr = prb + 4 * i;
        float m0 = -1e30f, m1 = -1e30f;

        #pragma unroll 1
        for (int s = 0; s < 4; ++s) {
            int y = pr * 2 + (s >> 1);
            int x = pc * 2 + (s & 1);

            // 9 dilated taps, both channels
            float hvx[9], hvy[9];
            #pragma unroll
            for (int t = 0; t < 9; ++t) {
                int yy = y + (t / 3 - 1) * 3;
                int xx = x + (t % 3 - 1) * 3;
                float a = 0.f, b = 0.f;
                if (yy >= 0 && yy < HH && xx >= 0 && xx < WW) {
                    const float* p = sh + ((size_t)(yy - row_lo) * WW + xx) * 2;
                    a = p[0]; b = p[1];
                }
                hvx[t] = a; hvy[t] = b;
            }

            float acc0 = 0.f, acc1 = 0.f;
            #pragma unroll 1
            for (int k = 0; k < 9; ++k) {
                const float* wy = WOFF + (2 * k) * 18;
                const float* wx = WOFF + (2 * k + 1) * 18;
                const float* wm = WOFF + (18 + k) * 18;
                float dyv = 0.f, dxv = 0.f, mv = 0.f;
                #pragma unroll
                for (int t = 0; t < 9; ++t) {
                    float ha = hvx[t], hcb = hvy[t];
                    dyv += ha * wy[t] + hcb * wy[9 + t];
                    dxv += ha * wx[t] + hcb * wx[9 + t];
                    mv  += ha * wm[t] + hcb * wm[9 + t];
                }
                float mod = 1.f / (1.f + __expf(-mv));

                float py  = (float)(y + (k / 3 - 1) * 3) + dyv;
                float pxx = (float)(x + (k % 3 - 1) * 3) + dxv;
                float y0f = floorf(py), x0f = floorf(pxx);
                int   y0 = (int)y0f,   x0 = (int)x0f;
                float ly = py - y0f,   lx = pxx - x0f;

                float a00, b00, a01, b01, a10, b10, a11, b11;
                fetch2(sh, h0, hb, row_lo, row_hi, y0,     x0,     a00, b00);
                fetch2(sh, h0, hb, row_lo, row_hi, y0,     x0 + 1, a01, b01);
                fetch2(sh, h0, hb, row_lo, row_hi, y0 + 1, x0,     a10, b10);
                fetch2(sh, h0, hb, row_lo, row_hi, y0 + 1, x0 + 1, a11, b11);

                float w00 = (1.f - ly) * (1.f - lx);
                float w01 = (1.f - ly) * lx;
                float w10 = ly * (1.f - lx);
                float w11 = ly * lx;
                float sA = (w00 * a00 + w01 * a01 + w10 * a10 + w11 * a11) * mod;
                float sB = (w00 * b00 + w01 * b01 + w10 * b10 + w11 * b11) * mod;

                acc0 += WDCN[k]      * sA + WDCN[9 + k]  * sB;
                acc1 += WDCN[18 + k] * sA + WDCN[27 + k] * sB;
            }

            float v0 = acc0 + BDCN[0];
            float v1 = acc1 + BDCN[1];
            float u0 = fmaxf(W2[0] * v0 + W2[1] * v1 + B2[0], 0.f);
            float u1 = fmaxf(W2[2] * v0 + W2[3] * v1 + B2[1], 0.f);
            m0 = fmaxf(m0, u0);
            m1 = fmaxf(m1, u1);
        }

        size_t pb = (size_t)n * FC1_IN + (size_t)pr * POOLD + pc;
        pooled[pb]        = m0;
        pooled[pb + 4096] = m1;
    }
}

// ---------------------------------------------------------------------------
// Kernel 3: bias init for both atomic GEMM outputs (fused)
// ---------------------------------------------------------------------------
__global__ void init_bias2_kernel(
    float* __restrict__ o1, const float* __restrict__ bb1,
    float* __restrict__ o2, const float* __restrict__ bb2)
{
    int i = blockIdx.x * blockDim.x + threadIdx.x;
    if (i < NB * FC1_OUT) o1[i] = bb1[i & (FC1_OUT - 1)];
    if (i < NB * FC2_OUT) o2[i] = bb2[i & (FC2_OUT - 1)];
}

// ---------------------------------------------------------------------------
// Kernel 4: f32 GEMM  C(128 x Nc) += A(128 x K) @ B(Nc x K)^T   (split-K atomic)
//   BM=128 BN=64 BK=32, 256 threads, 8x4 microtile
// ---------------------------------------------------------------------------
__global__ __launch_bounds__(256) void gemm_splitk_kernel(
    const float* __restrict__ A, const float* __restrict__ B,
    float* __restrict__ C, int K, int Nc, int kchunk, int relu_a)
{
    __shared__ float As[32][128];
    __shared__ float Bs[32][64];

    int tid = threadIdx.x;
    int jt  = blockIdx.x;            // N tile
    int k0  = blockIdx.y * kchunk;

    int tx = tid & 15;               // 0..15 -> 4 cols each
    int ty = tid >> 4;               // 0..15 -> 8 rows each

    float acc[8][4];
    #pragma unroll
    for (int i = 0; i < 8; ++i)
        #pragma unroll
        for (int j = 0; j < 4; ++j) acc[i][j] = 0.f;

    int lr = tid >> 3;               // 0..31
    int lc = (tid & 7) << 2;         // 0,4,...,28

    for (int kk0 = 0; kk0 < kchunk; kk0 += 32) {
        int kbase = k0 + kk0;
        #pragma unroll
        for (int p = 0; p < 4; ++p) {
            int row = lr + p * 32;
            float4 v = *(const float4*)(A + (size_t)row * K + kbase + lc);
            if (relu_a) {
                v.x = fmaxf(v.x, 0.f); v.y = fmaxf(v.y, 0.f);
                v.z = fmaxf(v.z, 0.f); v.w = fmaxf(v.w, 0.f);
            }
            As[lc + 0][row] = v.x; As[lc + 1][row] = v.y;
            As[lc + 2][row] = v.z; As[lc + 3][row] = v.w;
        }
        #pragma unroll
        for (int p = 0; p < 2; ++p) {
            int row = lr + p * 32;
            float4 v = *(const float4*)(B + (size_t)(jt * 64 + row) * K + kbase + lc);
            Bs[lc + 0][row] = v.x; Bs[lc + 1][row] = v.y;
            Bs[lc + 2][row] = v.z; Bs[lc + 3][row] = v.w;
        }
        __syncthreads();

        #pragma unroll
        for (int kk = 0; kk < 32; ++kk) {
            float4 a0 = *(const float4*)&As[kk][ty * 8];
            float4 a1 = *(const float4*)&As[kk][ty * 8 + 4];
            float4 b  = *(const float4*)&Bs[kk][tx * 4];
            float av[8] = {a0.x, a0.y, a0.z, a0.w, a1.x, a1.y, a1.z, a1.w};
            float bv[4] = {b.x, b.y, b.z, b.w};
            #pragma unroll
            for (int i = 0; i < 8; ++i)
                #pragma unroll
                for (int j = 0; j < 4; ++j)
                    acc[i][j] += av[i] * bv[j];
        }
        __syncthreads();
    }

    #pragma unroll
    for (int i = 0; i < 8; ++i) {
        int row = ty * 8 + i;
        #pragma unroll
        for (int j = 0; j < 4; ++j) {
            int col = jt * 64 + tx * 4 + j;
            atomicAdd(C + (size_t)row * Nc + col, acc[i][j]);
        }
    }
}

// ---------------------------------------------------------------------------
// Kernel 5: io layer  out[n] = sigmoid( relu(fc2[n,:]) . io_w + io_b )
// ---------------------------------------------------------------------------
__global__ __launch_bounds__(256) void io_kernel(
    const float* __restrict__ fc2o, const float* __restrict__ io_w,
    const float* __restrict__ io_b, float* __restrict__ out)
{
    int n = blockIdx.x;
    int tid = threadIdx.x;
    float s = 0.f;
    #pragma unroll
    for (int k = tid; k < FC2_OUT; k += 256)
        s += fmaxf(fc2o[(size_t)n * FC2_OUT + k], 0.f) * io_w[k];
    #pragma unroll
    for (int off = 32; off > 0; off >>= 1)
        s += __shfl_down(s, off, 64);
    __shared__ float red[4];
    if ((tid & 63) == 0) red[tid >> 6] = s;
    __syncthreads();
    if (tid == 0) {
        float t = red[0] + red[1] + red[2] + red[3] + io_b[0];
        out[n] = 1.f / (1.f + expf(-t));
    }
}

// ---------------------------------------------------------------------------
// launch
// ---------------------------------------------------------------------------
extern "C" void kernel_launch(void* const* d_in, const int* in_sizes, int n_in,
                              void* d_out, int out_size, void* d_ws, size_t ws_size,
                              hipStream_t stream)
{
    const float* mask  = (const float*)d_in[0];
    const float* x     = (const float*)d_in[1];
    const float* w1    = (const float*)d_in[2];
    const float* b1    = (const float*)d_in[3];
    const float* w_off = (const float*)d_in[4];
    const float* w_dcn = (const float*)d_in[5];
    const float* b_dcn = (const float*)d_in[6];
    const float* w2    = (const float*)d_in[7];
    const float* b2    = (const float*)d_in[8];
    const float* fc1_w = (const float*)d_in[9];
    const float* fc1_b = (const float*)d_in[10];
    const float* fc2_w = (const float*)d_in[11];
    const float* fc2_b = (const float*)d_in[12];
    const float* io_w  = (const float*)d_in[13];
    const float* io_b  = (const float*)d_in[14];

    float* ws      = (float*)d_ws;
    float* h1      = ws + H1_OFF;
    float* pooled  = ws + POOL_OFF;
    float* fc1_out = ws + FC1_OFF;
    float* fc2_out = ws + FC2_OFF;
    float* out     = (float*)d_out;

    // conv1: (N,9,128,128) -> h1 (N,2,128,128)
    conv1_kernel<<<dim3(16, NB), 256, 0, stream>>>(x, mask, w1, b1, h1);

    // fused offset-conv + DCN + 1x1 relu + 2x2 maxpool -> pooled (N,8192)
    fused_dcn_kernel<<<dim3(8, NB), 256, 0, stream>>>(
        h1, w_off, w_dcn, b_dcn, w2, b2, pooled);

    // bias init for atomic accumulation (fused)
    init_bias2_kernel<<<(NB * FC1_OUT + 255) / 256, 256, 0, stream>>>(
        fc1_out, fc1_b, fc2_out, fc2_b);

    // fc1: (128,8192)@(8192,2048) split-K 16 -> 32x16 = 512 blocks
    gemm_splitk_kernel<<<dim3(FC1_OUT / 64, 16), 256, 0, stream>>>(
        pooled, fc1_w, fc1_out, FC1_IN, FC1_OUT, FC1_IN / 16, 0);

    // fc2: relu(fc1) (128,2048)@(2048,1024) split-K 16 -> 16x16 = 256 blocks
    gemm_splitk_kernel<<<dim3(FC2_OUT / 64, 16), 256, 0, stream>>>(
        fc1_out, fc2_w, fc2_out, FC1_OUT, FC2_OUT, FC1_OUT / 16, 1);

    // io: relu(fc2) . io_w -> sigmoid -> out (128)
    io_kernel<<<NB, 256, 0, stream>>>(fc2_out, io_w, io_b, out);
}

// Round 5
// 334.204 us; speedup vs baseline: 5.1019x; 1.3829x over previous
//
#include <hip/hip_runtime.h>
#include <math.h>

// ---------------------------------------------------------------------------
// Problem constants
// ---------------------------------------------------------------------------
#define NB   128      // batch
#define HH   128
#define WW   128
#define HW   (HH*WW)          // 16384
#define POOLD 64              // pooled spatial
#define FC1_IN  8192          // 2*64*64
#define FC1_OUT 2048
#define FC2_OUT 1024

// workspace layout (in floats)
#define H1_OFF    0                       // 128*2*128*128 = 4194304
#define POOL_OFF  4194304                 // 128*8192      = 1048576
#define FC1_OFF   5242880                 // 128*2048      = 262144
#define FC2_OFF   5505024                 // 128*1024      = 131072

// ---------------------------------------------------------------------------
// Kernel 1: conv1  z=(x||mask) 9ch -> 2ch, 3x3, pad 1  ->  h1 (N,2,128,128)
// ---------------------------------------------------------------------------
__global__ __launch_bounds__(256) void conv1_kernel(
    const float* __restrict__ xin, const float* __restrict__ mask,
    const float* __restrict__ w1, const float* __restrict__ b1,
    float* __restrict__ h1)
{
    __shared__ float sw[164];              // 162 weights + 2 bias
    __shared__ float sh[9][10][132];       // ch x in-row x (col+1 pad each side)

    int tid = threadIdx.x;
    int n   = blockIdx.y;
    int r0  = blockIdx.x * 8;              // first output row of this block

    if (tid < 162) sw[tid] = w1[tid];
    if (tid < 2)   sw[162 + tid] = b1[tid];

    // zero the edge columns (global col -1 and 128)
    for (int i = tid; i < 90; i += 256) {
        int c  = i / 10;
        int ry = i - c * 10;
        sh[c][ry][0]   = 0.f;
        sh[c][ry][129] = 0.f;
    }

    // stage 9 x 10 x 128 floats as float4 rows (12 indep loads/thread)
    for (int idx = tid; idx < 2880; idx += 256) {
        int c   = idx / 320;
        int rem = idx - c * 320;
        int ry  = rem >> 5;
        int x4  = (rem & 31) << 2;
        int g   = r0 - 1 + ry;             // global input row
        float4 v = make_float4(0.f, 0.f, 0.f, 0.f);
        if (g >= 0 && g < HH) {
            const float* src = (c < 8) ? (xin + ((size_t)n * 8 + c) * HW)
                                       : (mask + (size_t)n * HW);
            v = *(const float4*)(src + (size_t)g * WW + x4);
        }
        float* d = &sh[c][ry][x4 + 1];
        d[0] = v.x; d[1] = v.y; d[2] = v.z; d[3] = v.w;
    }
    __syncthreads();

    int x  = tid & 127;                    // output col
    int yb = (tid >> 7) * 4;               // 0 or 4: first of 4 output rows

    float acc[4][2];
    #pragma unroll
    for (int r = 0; r < 4; ++r) { acc[r][0] = sw[162]; acc[r][1] = sw[163]; }

    for (int c = 0; c < 9; ++c) {
        float v[6][3];
        #pragma unroll
        for (int iy = 0; iy < 6; ++iy)
            #pragma unroll
            for (int kx = 0; kx < 3; ++kx)
                v[iy][kx] = sh[c][yb + iy][x + kx];
        #pragma unroll
        for (int r = 0; r < 4; ++r)
            #pragma unroll
            for (int ky = 0; ky < 3; ++ky)
                #pragma unroll
                for (int kx = 0; kx < 3; ++kx) {
                    float t = v[r + ky][kx];
                    acc[r][0] += t * sw[c * 9 + ky * 3 + kx];
                    acc[r][1] += t * sw[81 + c * 9 + ky * 3 + kx];
                }
    }

    #pragma unroll
    for (int r = 0; r < 4; ++r) {
        size_t base = (size_t)n * (2 * HW) + (size_t)(r0 + yb + r) * WW + x;
        h1[base]      = acc[r][0];
        h1[base + HW] = acc[r][1];
    }
}

// ---------------------------------------------------------------------------
// Kernel 2: fused  conv_off -> modulated deform conv -> 1x1+relu -> maxpool
// ---------------------------------------------------------------------------
#define HALO 8

__device__ __forceinline__ void fetch2(
    const float* __restrict__ sh, const float* __restrict__ h0,
    const float* __restrict__ hb, int row_lo, int row_hi,
    int yi, int xi, float& a, float& b)
{
    a = 0.f; b = 0.f;
    if (yi < 0 || yi >= HH || xi < 0 || xi >= WW) return;
    if (yi >= row_lo && yi < row_hi) {          // staged window (always, in practice)
        const float* p = sh + ((size_t)(yi - row_lo) * WW + xi) * 2;
        a = p[0]; b = p[1];
    } else {                                    // rare fallback: |offset| > HALO-5
        a = h0[yi * WW + xi];
        b = hb[yi * WW + xi];
    }
}

__global__ __launch_bounds__(256, 4) void fused_dcn_kernel(
    const float* __restrict__ h1,
    const float* __restrict__ w_off,   // (27,2,3,3)
    const float* __restrict__ w_dcn,   // (2,2,3,3)
    const float* __restrict__ b_dcn,   // (2)
    const float* __restrict__ w2,      // (2,2,1,1)
    const float* __restrict__ b2,      // (2)
    float* __restrict__ pooled)        // (N, 8192) = (N,2,64,64)
{
    __shared__ float sh[32 * WW * 2];      // 32 KB, interleaved (y,x,c)
    __shared__ float sw[530];

    int tid = threadIdx.x;
    int n   = blockIdx.y;
    int r0  = blockIdx.x * 16;             // full-res row base of this block

    for (int i = tid; i < 530; i += 256) {
        float v;
        if (i < 486)      v = w_off[i];
        else if (i < 522) v = w_dcn[i - 486];
        else if (i < 526) v = w2[i - 522];
        else if (i < 528) v = b_dcn[i - 526];
        else              v = b2[i - 528];
        sw[i] = v;
    }

    int row_lo = r0 - HALO;       if (row_lo < 0)   row_lo = 0;
    int row_hi = r0 + 16 + HALO;  if (row_hi > HH)  row_hi = HH;
    int rows = row_hi - row_lo;

    const float* h0 = h1 + (size_t)n * (2 * HW);
    const float* hb = h0 + HW;

    // stage h1 window: float4 per channel, interleave into LDS
    for (int idx = tid; idx < rows * 32; idx += 256) {
        int ry = idx >> 5;
        int x4 = (idx & 31) << 2;
        const float4 a = *(const float4*)(h0 + (size_t)(row_lo + ry) * WW + x4);
        const float4 b = *(const float4*)(hb + (size_t)(row_lo + ry) * WW + x4);
        float* d = sh + ((size_t)ry * WW + x4) * 2;
        d[0] = a.x; d[1] = b.x; d[2] = a.y; d[3] = b.y;
        d[4] = a.z; d[5] = b.z; d[6] = a.w; d[7] = b.w;
    }
    __syncthreads();

    const float* WOFF = sw;
    const float* WDCN = sw + 486;
    const float* W2   = sw + 522;
    const float* BDCN = sw + 526;
    const float* B2   = sw + 528;

    int pc  = tid & 63;                     // pooled col 0..63
    int prb = blockIdx.x * 8 + (tid >> 6);  // pooled row base (warp-row 0..3)

    #pragma unroll 1
    for (int i = 0; i < 2; ++i) {
        int pr = prb + 4 * i;
        float m0 = -1e30f, m1 = -1e30f;

        #pragma unroll 1
        for (int s = 0; s < 4; ++s) {
            int y = pr * 2 + (s >> 1);
            int x = pc * 2 + (s & 1);

            // 9 dilated taps, both channels
            float hvx[9], hvy[9];
            #pragma unroll
            for (int t = 0; t < 9; ++t) {
                int yy = y + (t / 3 - 1) * 3;
                int xx = x + (t % 3 - 1) * 3;
                float a = 0.f, b = 0.f;
                if (yy >= 0 && yy < HH && xx >= 0 && xx < WW) {
                    const float* p = sh + ((size_t)(yy - row_lo) * WW + xx) * 2;
                    a = p[0]; b = p[1];
                }
                hvx[t] = a; hvy[t] = b;
            }

            float acc0 = 0.f, acc1 = 0.f;
            #pragma unroll 1
            for (int k = 0; k < 9; ++k) {
                const float* wy = WOFF + (2 * k) * 18;
                const float* wx = WOFF + (2 * k + 1) * 18;
                const float* wm = WOFF + (18 + k) * 18;
                float dyv = 0.f, dxv = 0.f, mv = 0.f;
                #pragma unroll
                for (int t = 0; t < 9; ++t) {
                    float ha = hvx[t], hcb = hvy[t];
                    dyv += ha * wy[t] + hcb * wy[9 + t];
                    dxv += ha * wx[t] + hcb * wx[9 + t];
                    mv  += ha * wm[t] + hcb * wm[9 + t];
                }
                float mod = 1.f / (1.f + __expf(-mv));

                float py  = (float)(y + (k / 3 - 1) * 3) + dyv;
                float pxx = (float)(x + (k % 3 - 1) * 3) + dxv;
                float y0f = floorf(py), x0f = floorf(pxx);
                int   y0 = (int)y0f,   x0 = (int)x0f;
                float ly = py - y0f,   lx = pxx - x0f;

                float a00, b00, a01, b01, a10, b10, a11, b11;
                fetch2(sh, h0, hb, row_lo, row_hi, y0,     x0,     a00, b00);
                fetch2(sh, h0, hb, row_lo, row_hi, y0,     x0 + 1, a01, b01);
                fetch2(sh, h0, hb, row_lo, row_hi, y0 + 1, x0,     a10, b10);
                fetch2(sh, h0, hb, row_lo, row_hi, y0 + 1, x0 + 1, a11, b11);

                float w00 = (1.f - ly) * (1.f - lx);
                float w01 = (1.f - ly) * lx;
                float w10 = ly * (1.f - lx);
                float w11 = ly * lx;
                float sA = (w00 * a00 + w01 * a01 + w10 * a10 + w11 * a11) * mod;
                float sB = (w00 * b00 + w01 * b01 + w10 * b10 + w11 * b11) * mod;

                acc0 += WDCN[k]      * sA + WDCN[9 + k]  * sB;
                acc1 += WDCN[18 + k] * sA + WDCN[27 + k] * sB;
            }

            float v0 = acc0 + BDCN[0];
            float v1 = acc1 + BDCN[1];
            float u0 = fmaxf(W2[0] * v0 + W2[1] * v1 + B2[0], 0.f);
            float u1 = fmaxf(W2[2] * v0 + W2[3] * v1 + B2[1], 0.f);
            m0 = fmaxf(m0, u0);
            m1 = fmaxf(m1, u1);
        }

        size_t pb = (size_t)n * FC1_IN + (size_t)pr * POOLD + pc;
        pooled[pb]        = m0;
        pooled[pb + 4096] = m1;
    }
}

// ---------------------------------------------------------------------------
// Kernel 3: bias init for both atomic GEMM outputs (fused)
// ---------------------------------------------------------------------------
__global__ void init_bias2_kernel(
    float* __restrict__ o1, const float* __restrict__ bb1,
    float* __restrict__ o2, const float* __restrict__ bb2)
{
    int i = blockIdx.x * blockDim.x + threadIdx.x;
    if (i < NB * FC1_OUT) o1[i] = bb1[i & (FC1_OUT - 1)];
    if (i < NB * FC2_OUT) o2[i] = bb2[i & (FC2_OUT - 1)];
}

// ---------------------------------------------------------------------------
// Kernel 4: bf16-MFMA GEMM  C(128 x Nc) += A(128 x K) @ B(Nc x K)^T  (split-K)
//   f32 inputs converted to bf16 in-register during LDS staging.
//   BM=128 BN=64 BK=32; 4 waves x (2 m-tiles x 4 n-tiles) mfma_16x16x32_bf16.
//   LDS row stride 40 bf16: 16B-aligned b128 frags, worst 2-way conflict.
// ---------------------------------------------------------------------------
typedef __bf16 bf16x8 __attribute__((ext_vector_type(8)));
typedef float  f32x4  __attribute__((ext_vector_type(4)));

#define LDT 40

__device__ __forceinline__ unsigned short f2bf(float f) {
    unsigned int u = __float_as_uint(f);
    return (unsigned short)((u + 0x7fffu + ((u >> 16) & 1u)) >> 16);
}

__global__ __launch_bounds__(256) void gemm_bf16_splitk(
    const float* __restrict__ A, const float* __restrict__ B,
    float* __restrict__ C, int K, int Nc, int kchunk, int relu_a)
{
    __shared__ __align__(16) unsigned short As[128 * LDT];
    __shared__ __align__(16) unsigned short Bs[64 * LDT];

    int tid = threadIdx.x;
    int jt  = blockIdx.x;                  // N tile (64 cols)
    int k0  = blockIdx.y * kchunk;
    int iters = kchunk >> 5;

    int t8  = tid >> 3;                    // 0..31 row group
    int c16 = (tid & 7) << 2;              // f32 col offset 0,4,..,28

    const float* Ag = A + (size_t)t8 * K + k0 + c16;
    const float* Bg = B + (size_t)(jt * 64 + t8) * K + k0 + c16;

    float4 pa[4]; float4 pb[2];
    #pragma unroll
    for (int p = 0; p < 4; ++p) pa[p] = *(const float4*)(Ag + (size_t)(p * 32) * K);
    #pragma unroll
    for (int p = 0; p < 2; ++p) pb[p] = *(const float4*)(Bg + (size_t)(p * 32) * K);

    int lane = tid & 63;
    int w    = tid >> 6;                   // wave 0..3 -> rows w*32..w*32+31
    int quad = lane >> 4;
    int r    = lane & 15;

    f32x4 acc[2][4];
    #pragma unroll
    for (int mt = 0; mt < 2; ++mt)
        #pragma unroll
        for (int nt = 0; nt < 4; ++nt)
            acc[mt][nt] = (f32x4){0.f, 0.f, 0.f, 0.f};

    for (int it = 0; it < iters; ++it) {
        // write prefetched f32 regs -> LDS as bf16
        #pragma unroll
        for (int p = 0; p < 4; ++p) {
            float4 v = pa[p];
            if (relu_a) {
                v.x = fmaxf(v.x, 0.f); v.y = fmaxf(v.y, 0.f);
                v.z = fmaxf(v.z, 0.f); v.w = fmaxf(v.w, 0.f);
            }
            ushort4 s = make_ushort4(f2bf(v.x), f2bf(v.y), f2bf(v.z), f2bf(v.w));
            *(ushort4*)&As[(t8 + p * 32) * LDT + c16] = s;
        }
        #pragma unroll
        for (int p = 0; p < 2; ++p) {
            float4 v = pb[p];
            ushort4 s = make_ushort4(f2bf(v.x), f2bf(v.y), f2bf(v.z), f2bf(v.w));
            *(ushort4*)&Bs[(t8 + p * 32) * LDT + c16] = s;
        }
        __syncthreads();

        // prefetch next k-tile while computing this one
        if (it + 1 < iters) {
            Ag += 32; Bg += 32;
            #pragma unroll
            for (int p = 0; p < 4; ++p) pa[p] = *(const float4*)(Ag + (size_t)(p * 32) * K);
            #pragma unroll
            for (int p = 0; p < 2; ++p) pb[p] = *(const float4*)(Bg + (size_t)(p * 32) * K);
        }

        bf16x8 af[2];
        #pragma unroll
        for (int mt = 0; mt < 2; ++mt)
            af[mt] = *(const bf16x8*)&As[(w * 32 + mt * 16 + r) * LDT + quad * 8];
        bf16x8 bfr[4];
        #pragma unroll
        for (int nt = 0; nt < 4; ++nt)
            bfr[nt] = *(const bf16x8*)&Bs[(nt * 16 + r) * LDT + quad * 8];

        #pragma unroll
        for (int mt = 0; mt < 2; ++mt)
            #pragma unroll
            for (int nt = 0; nt < 4; ++nt)
                acc[mt][nt] = __builtin_amdgcn_mfma_f32_16x16x32_bf16(
                    af[mt], bfr[nt], acc[mt][nt], 0, 0, 0);

        __syncthreads();
    }

    // epilogue: C/D layout col = lane&15, row = quad*4 + reg  (m89-verified)
    #pragma unroll
    for (int mt = 0; mt < 2; ++mt) {
        int mrow = w * 32 + mt * 16 + quad * 4;
        #pragma unroll
        for (int nt = 0; nt < 4; ++nt) {
            int col = jt * 64 + nt * 16 + r;
            #pragma unroll
            for (int i = 0; i < 4; ++i)
                atomicAdd(C + (size_t)(mrow + i) * Nc + col, acc[mt][nt][i]);
        }
    }
}

// ---------------------------------------------------------------------------
// Kernel 5: io layer  out[n] = sigmoid( relu(fc2[n,:]) . io_w + io_b )
// ---------------------------------------------------------------------------
__global__ __launch_bounds__(256) void io_kernel(
    const float* __restrict__ fc2o, const float* __restrict__ io_w,
    const float* __restrict__ io_b, float* __restrict__ out)
{
    int n = blockIdx.x;
    int tid = threadIdx.x;
    float s = 0.f;
    #pragma unroll
    for (int k = tid; k < FC2_OUT; k += 256)
        s += fmaxf(fc2o[(size_t)n * FC2_OUT + k], 0.f) * io_w[k];
    #pragma unroll
    for (int off = 32; off > 0; off >>= 1)
        s += __shfl_down(s, off, 64);
    __shared__ float red[4];
    if ((tid & 63) == 0) red[tid >> 6] = s;
    __syncthreads();
    if (tid == 0) {
        float t = red[0] + red[1] + red[2] + red[3] + io_b[0];
        out[n] = 1.f / (1.f + expf(-t));
    }
}

// ---------------------------------------------------------------------------
// launch
// ---------------------------------------------------------------------------
extern "C" void kernel_launch(void* const* d_in, const int* in_sizes, int n_in,
                              void* d_out, int out_size, void* d_ws, size_t ws_size,
                              hipStream_t stream)
{
    const float* mask  = (const float*)d_in[0];
    const float* x     = (const float*)d_in[1];
    const float* w1    = (const float*)d_in[2];
    const float* b1    = (const float*)d_in[3];
    const float* w_off = (const float*)d_in[4];
    const float* w_dcn = (const float*)d_in[5];
    const float* b_dcn = (const float*)d_in[6];
    const float* w2    = (const float*)d_in[7];
    const float* b2    = (const float*)d_in[8];
    const float* fc1_w = (const float*)d_in[9];
    const float* fc1_b = (const float*)d_in[10];
    const float* fc2_w = (const float*)d_in[11];
    const float* fc2_b = (const float*)d_in[12];
    const float* io_w  = (const float*)d_in[13];
    const float* io_b  = (const float*)d_in[14];

    float* ws      = (float*)d_ws;
    float* h1      = ws + H1_OFF;
    float* pooled  = ws + POOL_OFF;
    float* fc1_out = ws + FC1_OFF;
    float* fc2_out = ws + FC2_OFF;
    float* out     = (float*)d_out;

    // conv1: (N,9,128,128) -> h1 (N,2,128,128)
    conv1_kernel<<<dim3(16, NB), 256, 0, stream>>>(x, mask, w1, b1, h1);

    // fused offset-conv + DCN + 1x1 relu + 2x2 maxpool -> pooled (N,8192)
    fused_dcn_kernel<<<dim3(8, NB), 256, 0, stream>>>(
        h1, w_off, w_dcn, b_dcn, w2, b2, pooled);

    // bias init for atomic accumulation (fused)
    init_bias2_kernel<<<(NB * FC1_OUT + 255) / 256, 256, 0, stream>>>(
        fc1_out, fc1_b, fc2_out, fc2_b);

    // fc1: (128,8192)@(8192,2048)  bf16 MFMA, split-K 16 -> 32x16 = 512 blocks
    gemm_bf16_splitk<<<dim3(FC1_OUT / 64, 16), 256, 0, stream>>>(
        pooled, fc1_w, fc1_out, FC1_IN, FC1_OUT, FC1_IN / 16, 0);

    // fc2: relu(fc1) (128,2048)@(2048,1024)  bf16 MFMA, split-K 16 -> 256 blocks
    gemm_bf16_splitk<<<dim3(FC2_OUT / 64, 16), 256, 0, stream>>>(
        fc1_out, fc2_w, fc2_out, FC1_OUT, FC2_OUT, FC1_OUT / 16, 1);

    // io: relu(fc2) . io_w -> sigmoid -> out (128)
    io_kernel<<<NB, 256, 0, stream>>>(fc2_out, io_w, io_b, out);
}